// Round 1
// 1040.272 us; speedup vs baseline: 1.2548x; 1.2548x over previous
//
#include <hip/hip_runtime.h>
#include <cstdint>
#include <cstddef>

// ---------------------------------------------------------------------------
// RNN_Decoder: B=64, T=50, E=H=512, V=30000, fp32 in/out, bf16 MFMA compute.
// Pipeline: prep (bf16 casts + embed gather) -> G0 = X@W_ih^T + biases (MFMA)
//           -> ONE persistent LSTM kernel (50 steps, W_hh in VGPRs, c in regs,
//              hand-rolled device-scope grid barrier between steps)
//           -> out = Hs@W_fc^T + b_fc (MFMA, permuted store [t,b]->[b,t]).
// ---------------------------------------------------------------------------

typedef short bf16x8 __attribute__((ext_vector_type(8)));   // 8 bf16 = 4 VGPRs
typedef float f32x4 __attribute__((ext_vector_type(4)));

#define B_    64
#define T_    50
#define E_    512
#define H_    512
#define V_    30000
#define VPAD  30080      // 235 * 128, padded rows of W_fc are zero
#define TB_   3200       // T_*B_

__device__ __forceinline__ unsigned short f2bf(float f) {
  // round-to-nearest-even f32 -> bf16 (inputs are finite; no NaN path needed)
  unsigned int u = __float_as_uint(f);
  u += 0x7fffu + ((u >> 16) & 1u);
  return (unsigned short)(u >> 16);
}

__device__ __forceinline__ void async_copy16(const void* g, void* l) {
  // global -> LDS direct copy, 16B per lane. LDS dest must be
  // wave-uniform-base + lane*16 (guide §5 caveat) — all call sites satisfy it.
  __builtin_amdgcn_global_load_lds(
      (__attribute__((address_space(1))) void*)g,
      (__attribute__((address_space(3))) void*)l, 16, 0, 0);
}

// ---------------------------- prep kernels ---------------------------------

__global__ __launch_bounds__(256) void convert_bf16_kernel(
    const float* __restrict__ src, unsigned short* __restrict__ dst, int n) {
  int i = blockIdx.x * 256 + threadIdx.x;
  if (i < n) dst[i] = f2bf(src[i]);
}

__global__ __launch_bounds__(256) void convert_pad_wfc_kernel(
    const float* __restrict__ src, unsigned short* __restrict__ dst) {
  int i = blockIdx.x * 256 + threadIdx.x;  // over VPAD*512
  if (i >= VPAD * 512) return;
  int row = i >> 9;
  dst[i] = (row < V_) ? f2bf(src[i]) : (unsigned short)0;
}

__global__ __launch_bounds__(256) void build_x_kernel(
    const float* __restrict__ x, const int* __restrict__ caption,
    const float* __restrict__ emb, unsigned short* __restrict__ X) {
  int i = blockIdx.x * 256 + threadIdx.x;  // over TB_*512
  if (i >= TB_ * 512) return;
  int r = i >> 9, e = i & 511;
  int t = r >> 6, b = r & 63;
  float v = (t == 0) ? x[b * 512 + e]
                     : emb[(size_t)caption[b * T_ + t] * 512 + e];
  X[i] = f2bf(v);
}

// Zero Hs block 0 (the h_{-1} = 0 state) and the grid-barrier counter.
// Runs every graph replay, so the monotonic counter restarts at 0 each run.
__global__ __launch_bounds__(256) void zero_state_kernel(
    unsigned short* __restrict__ hs0, int* __restrict__ cnt) {
  int i = blockIdx.x * 256 + threadIdx.x;
  if (i < B_ * H_) hs0[i] = 0;
  if (i == 0) *cnt = 0;
}

// ------------------- GEMM: G0 = X @ W_ih^T + b_ih + b_hh -------------------
// m97 structure: 128x128 tile, BK=32, 4 waves (2x2 of 64x64), 16x16x32 MFMA.

__global__ __launch_bounds__(256) void gemm_g0_kernel(
    const unsigned short* __restrict__ A,    // X_bf [3200][512]
    const unsigned short* __restrict__ Bm,   // Wih_bf [2048][512] (n-major)
    const float* __restrict__ b_ih, const float* __restrict__ b_hh,
    float* __restrict__ G0) {                // [3200][2048]
  __shared__ __align__(16) unsigned short As[128 * 32];
  __shared__ __align__(16) unsigned short Bs[128 * 32];
  const int tid = threadIdx.x;
  const int lane = tid & 63;
  const int w = tid >> 6;
  const int wm = (w >> 1) * 64;
  const int wn = (w & 1) * 64;
  const int m0 = blockIdx.y * 128;
  const int n0 = blockIdx.x * 128;
  const int srow = w * 16 + (lane >> 2);     // staging: lds off = w*1024 + lane*16
  const int skoff = (lane & 3) * 8;

  const f32x4 fzero = {0.f, 0.f, 0.f, 0.f};
  f32x4 acc[4][4];
#pragma unroll
  for (int i = 0; i < 4; i++)
#pragma unroll
    for (int j = 0; j < 4; j++) acc[i][j] = fzero;

  for (int k0 = 0; k0 < 512; k0 += 32) {
    async_copy16(A + (size_t)(m0 + srow) * 512 + k0 + skoff, &As[srow * 32 + skoff]);
    async_copy16(A + (size_t)(m0 + srow + 64) * 512 + k0 + skoff, &As[(srow + 64) * 32 + skoff]);
    async_copy16(Bm + (size_t)(n0 + srow) * 512 + k0 + skoff, &Bs[srow * 32 + skoff]);
    async_copy16(Bm + (size_t)(n0 + srow + 64) * 512 + k0 + skoff, &Bs[(srow + 64) * 32 + skoff]);
    __syncthreads();
    const int fr = lane & 15;
    const int fk = (lane >> 4) * 8;
    bf16x8 af[4], bfv[4];
#pragma unroll
    for (int i = 0; i < 4; i++) {
      af[i] = *(const bf16x8*)&As[(wm + i * 16 + fr) * 32 + fk];
      bfv[i] = *(const bf16x8*)&Bs[(wn + i * 16 + fr) * 32 + fk];
    }
#pragma unroll
    for (int i = 0; i < 4; i++)
#pragma unroll
      for (int j = 0; j < 4; j++)
        acc[i][j] = __builtin_amdgcn_mfma_f32_16x16x32_bf16(af[i], bfv[j], acc[i][j], 0, 0, 0);
    __syncthreads();
  }
  const int quad = lane >> 4;
  const int colj = lane & 15;
#pragma unroll
  for (int j = 0; j < 4; j++) {
    const int n = n0 + wn + j * 16 + colj;
    const float bv = b_ih[n] + b_hh[n];
#pragma unroll
    for (int i = 0; i < 4; i++) {
      const int rb = m0 + wm + i * 16 + quad * 4;
#pragma unroll
      for (int p = 0; p < 4; p++)
        G0[(size_t)(rb + p) * 2048 + n] = acc[i][j][p] + bv;
    }
  }
}

// --------------------- persistent LSTM kernel ------------------------------
// ONE kernel for all 50 steps. grid = 32 WGs x 256 (4 waves), one WG per CU,
// guaranteed co-resident (32 <= 256 CUs, 1 wave/SIMD, no LDS) -> the spin
// barrier cannot deadlock.
//   WG j0=bid*16 owns h-columns [j0,j0+16) across all 4 gates.
//   Wave w owns batch rows [w*16, w*16+16).
//   W_hh B-fragments are step-invariant: hoisted into 256 VGPRs ONCE.
//   c lives in 4 VGPRs per lane (lane exclusively owns its (b,j) cells).
//   h exchange: step t reads HsX block t, writes block t+1 (disjoint ->
//   one device-scope barrier per step suffices). Block 0 is the zero state;
//   gemm_out consumes HsX+64*512 as Hs.
// Cross-XCD visibility: __threadfence() release (buffer_wbl2) before the
// atomic arrive; __threadfence() acquire (buffer_inv) after release — the
// guide-sanctioned device-scope pattern (§6 G16).

__global__ __launch_bounds__(256, 1) void lstm_persistent_kernel(
    const unsigned short* __restrict__ Whh,    // [2048][512] bf16
    const float* __restrict__ G0,              // [3200][2048]
    unsigned short* __restrict__ HsX,          // [(T_+1)*64][512] bf16
    int* __restrict__ cnt) {                   // grid barrier counter (zeroed)
  const int tid = threadIdx.x;
  const int lane = tid & 63;
  const int w = tid >> 6;
  const int j0 = blockIdx.x * 16;
  const int fr = lane & 15;
  const int quad = lane >> 4;
  const int fk = quad * 8;
  const int j = j0 + fr;                       // h column this lane owns

  // Hoist step-invariant W_hh fragments: 4 gates x 16 k-slices x 4 VGPRs.
  bf16x8 bfrag[4][16];
#pragma unroll
  for (int g = 0; g < 4; g++)
#pragma unroll
    for (int ks = 0; ks < 16; ks++)
      bfrag[g][ks] = *(const bf16x8*)&Whh[(size_t)(g * 512 + j0 + fr) * 512 + ks * 32 + fk];

  float creg[4] = {0.f, 0.f, 0.f, 0.f};       // c for (b = w*16+quad*4+p, j)
  const f32x4 fzero = {0.f, 0.f, 0.f, 0.f};

  for (int t = 0; t < T_; t++) {
    // A fragments: h_{t-1} = HsX block t. Issue all 16 loads up front.
    const unsigned short* arow = HsX + (size_t)(t * 64 + w * 16 + fr) * 512 + fk;
    bf16x8 af[16];
#pragma unroll
    for (int ks = 0; ks < 16; ks++) af[ks] = *(const bf16x8*)(arow + (size_t)ks * 32);

    // Prefetch G0 gate values so L3 latency hides under the MFMA chain.
    float g0v[4][4];                           // [gate][p]
#pragma unroll
    for (int p = 0; p < 4; p++) {
      const float* g0r = G0 + (size_t)(t * 64 + w * 16 + quad * 4 + p) * 2048 + j;
#pragma unroll
      for (int g = 0; g < 4; g++) g0v[g][p] = g0r[g * 512];
    }

    f32x4 acc[4] = {fzero, fzero, fzero, fzero};
#pragma unroll
    for (int ks = 0; ks < 16; ks++)
#pragma unroll
      for (int g = 0; g < 4; g++)
        acc[g] = __builtin_amdgcn_mfma_f32_16x16x32_bf16(af[ks], bfrag[g][ks], acc[g], 0, 0, 0);

#pragma unroll
    for (int p = 0; p < 4; p++) {
      float iv = acc[0][p] + g0v[0][p];
      float fv = acc[1][p] + g0v[1][p];
      float gv = acc[2][p] + g0v[2][p];
      float ov = acc[3][p] + g0v[3][p];
      iv = 1.f / (1.f + __expf(-iv));
      fv = 1.f / (1.f + __expf(-fv));
      gv = tanhf(gv);
      ov = 1.f / (1.f + __expf(-ov));
      float cn = fv * creg[p] + iv * gv;
      creg[p] = cn;
      float hn = ov * tanhf(cn);
      const int b = w * 16 + quad * 4 + p;
      HsX[(size_t)((t + 1) * 64 + b) * 512 + j] = f2bf(hn);
    }

    // Grid barrier (skip after the last step; kernel end + stream order
    // cover gemm_out). Monotonic target avoids counter-reset races.
    if (t != T_ - 1) {
      __syncthreads();
      if (tid == 0) {
        __threadfence();                       // release: drain h writes to L2+wb
        atomicAdd(cnt, 1);                     // device-scope by default
        const int target = 32 * (t + 1);
        while (__hip_atomic_load(cnt, __ATOMIC_RELAXED, __HIP_MEMORY_SCOPE_AGENT) < target)
          __builtin_amdgcn_s_sleep(1);
      }
      __syncthreads();
      __threadfence();                         // acquire: invalidate L1 for fresh h
    }
  }
}

// ----------------- GEMM: out[b,t,v] = Hs @ W_fc^T + b_fc -------------------

__global__ __launch_bounds__(256) void gemm_out_kernel(
    const unsigned short* __restrict__ A,    // Hs [3200][512]
    const unsigned short* __restrict__ Bm,   // Wfc_bf [30080][512] (padded)
    const float* __restrict__ bias,          // b_fc [30000]
    float* __restrict__ out) {               // [64][50][30000]
  __shared__ __align__(16) unsigned short As[128 * 32];
  __shared__ __align__(16) unsigned short Bs[128 * 32];
  const int tid = threadIdx.x;
  const int lane = tid & 63;
  const int w = tid >> 6;
  const int wm = (w >> 1) * 64;
  const int wn = (w & 1) * 64;
  const int m0 = blockIdx.y * 128;
  const int n0 = blockIdx.x * 128;
  const int srow = w * 16 + (lane >> 2);
  const int skoff = (lane & 3) * 8;

  const f32x4 fzero = {0.f, 0.f, 0.f, 0.f};
  f32x4 acc[4][4];
#pragma unroll
  for (int i = 0; i < 4; i++)
#pragma unroll
    for (int j = 0; j < 4; j++) acc[i][j] = fzero;

  for (int k0 = 0; k0 < 512; k0 += 32) {
    async_copy16(A + (size_t)(m0 + srow) * 512 + k0 + skoff, &As[srow * 32 + skoff]);
    async_copy16(A + (size_t)(m0 + srow + 64) * 512 + k0 + skoff, &As[(srow + 64) * 32 + skoff]);
    async_copy16(Bm + (size_t)(n0 + srow) * 512 + k0 + skoff, &Bs[srow * 32 + skoff]);
    async_copy16(Bm + (size_t)(n0 + srow + 64) * 512 + k0 + skoff, &Bs[(srow + 64) * 32 + skoff]);
    __syncthreads();
    const int fr = lane & 15;
    const int fk = (lane >> 4) * 8;
    bf16x8 af[4], bfv[4];
#pragma unroll
    for (int i = 0; i < 4; i++) {
      af[i] = *(const bf16x8*)&As[(wm + i * 16 + fr) * 32 + fk];
      bfv[i] = *(const bf16x8*)&Bs[(wn + i * 16 + fr) * 32 + fk];
    }
#pragma unroll
    for (int i = 0; i < 4; i++)
#pragma unroll
      for (int j = 0; j < 4; j++)
        acc[i][j] = __builtin_amdgcn_mfma_f32_16x16x32_bf16(af[i], bfv[j], acc[i][j], 0, 0, 0);
    __syncthreads();
  }
  const int quad = lane >> 4;
  const int colj = lane & 15;
#pragma unroll
  for (int j = 0; j < 4; j++) {
    const int v = n0 + wn + j * 16 + colj;
    if (v >= V_) continue;                 // only last col-tile partially valid
    const float bv = bias[v];
#pragma unroll
    for (int i = 0; i < 4; i++) {
      const int rb = m0 + wm + i * 16 + quad * 4;
#pragma unroll
      for (int p = 0; p < 4; p++) {
        const int r = rb + p;              // r = t*64 + b
        const int tt = r >> 6, bb = r & 63;
        out[(size_t)(bb * T_ + tt) * V_ + v] = acc[i][j][p] + bv;
      }
    }
  }
}

// ------------------------------- launch ------------------------------------

extern "C" void kernel_launch(void* const* d_in, const int* in_sizes, int n_in,
                              void* d_out, int out_size, void* d_ws, size_t ws_size,
                              hipStream_t stream) {
  const float* x       = (const float*)d_in[0];
  const int*   caption = (const int*)d_in[1];
  const float* emb     = (const float*)d_in[2];
  const float* W_ih    = (const float*)d_in[3];
  const float* W_hh    = (const float*)d_in[4];
  const float* b_ih    = (const float*)d_in[5];
  const float* b_hh    = (const float*)d_in[6];
  const float* W_fc    = (const float*)d_in[7];
  const float* b_fc    = (const float*)d_in[8];
  float* out = (float*)d_out;

  char* p = (char*)d_ws;
  auto alloc = [&](size_t bytes) {
    char* r = p;
    p += (bytes + 255) & ~(size_t)255;
    return r;
  };
  unsigned short* Wih_bf = (unsigned short*)alloc((size_t)2048 * 512 * 2);
  unsigned short* Whh_bf = (unsigned short*)alloc((size_t)2048 * 512 * 2);
  unsigned short* Wfc_bf = (unsigned short*)alloc((size_t)VPAD * 512 * 2);
  unsigned short* X_bf   = (unsigned short*)alloc((size_t)TB_ * 512 * 2);
  unsigned short* HsX    = (unsigned short*)alloc((size_t)(TB_ + 64) * 512 * 2);
  int*            cnt    = (int*)alloc(256);
  float* G0              = (float*)alloc((size_t)TB_ * 2048 * 4);
  // total ws use: ~68 MB

  unsigned short* Hs = HsX + (size_t)64 * 512;   // blocks 1..T_ = h_0..h_{T-1}

  convert_bf16_kernel<<<(2048 * 512 + 255) / 256, 256, 0, stream>>>(W_ih, Wih_bf, 2048 * 512);
  convert_bf16_kernel<<<(2048 * 512 + 255) / 256, 256, 0, stream>>>(W_hh, Whh_bf, 2048 * 512);
  convert_pad_wfc_kernel<<<(VPAD * 512 + 255) / 256, 256, 0, stream>>>(W_fc, Wfc_bf);
  build_x_kernel<<<(TB_ * 512 + 255) / 256, 256, 0, stream>>>(x, caption, emb, X_bf);
  zero_state_kernel<<<(B_ * H_ + 255) / 256, 256, 0, stream>>>(HsX, cnt);

  gemm_g0_kernel<<<dim3(16, 25), 256, 0, stream>>>(X_bf, Wih_bf, b_ih, b_hh, G0);

  lstm_persistent_kernel<<<32, 256, 0, stream>>>(Whh_bf, G0, HsX, cnt);

  gemm_out_kernel<<<dim3(235, 25), 256, 0, stream>>>(Hs, Wfc_bf, b_fc, out);
}

// Round 2
// 988.739 us; speedup vs baseline: 1.3202x; 1.0521x over previous
//
#include <hip/hip_runtime.h>
#include <cstdint>
#include <cstddef>

// ---------------------------------------------------------------------------
// RNN_Decoder: B=64, T=50, E=H=512, V=30000, fp32 in/out, bf16 MFMA compute.
// Pipeline: prep (bf16 casts + embed gather) -> G0 = X@W_ih^T + biases (MFMA)
//           -> ONE persistent LSTM kernel (50 steps, W_hh in VGPRs, c in regs,
//              h exchanged via AGENT-scope coherent loads/stores; barrier is
//              vmcnt-drain + relaxed atomic — NO buffer_wbl2/buffer_inv)
//           -> out = Hs@W_fc^T + b_fc (MFMA, permuted store [t,b]->[b,t]).
// ---------------------------------------------------------------------------

typedef short bf16x8 __attribute__((ext_vector_type(8)));   // 8 bf16 = 4 VGPRs
typedef float f32x4 __attribute__((ext_vector_type(4)));

#define B_    64
#define T_    50
#define E_    512
#define H_    512
#define V_    30000
#define VPAD  30080      // 235 * 128, padded rows of W_fc are zero
#define TB_   3200       // T_*B_

__device__ __forceinline__ unsigned short f2bf(float f) {
  // round-to-nearest-even f32 -> bf16 (inputs are finite; no NaN path needed)
  unsigned int u = __float_as_uint(f);
  u += 0x7fffu + ((u >> 16) & 1u);
  return (unsigned short)(u >> 16);
}

__device__ __forceinline__ void async_copy16(const void* g, void* l) {
  // global -> LDS direct copy, 16B per lane. LDS dest must be
  // wave-uniform-base + lane*16 (guide §5 caveat) — all call sites satisfy it.
  __builtin_amdgcn_global_load_lds(
      (__attribute__((address_space(1))) void*)g,
      (__attribute__((address_space(3))) void*)l, 16, 0, 0);
}

// ---------------------------- prep kernels ---------------------------------

__global__ __launch_bounds__(256) void convert_bf16_kernel(
    const float* __restrict__ src, unsigned short* __restrict__ dst, int n) {
  int i = blockIdx.x * 256 + threadIdx.x;
  if (i < n) dst[i] = f2bf(src[i]);
}

__global__ __launch_bounds__(256) void convert_pad_wfc_kernel(
    const float* __restrict__ src, unsigned short* __restrict__ dst) {
  int i = blockIdx.x * 256 + threadIdx.x;  // over VPAD*512
  if (i >= VPAD * 512) return;
  int row = i >> 9;
  dst[i] = (row < V_) ? f2bf(src[i]) : (unsigned short)0;
}

__global__ __launch_bounds__(256) void build_x_kernel(
    const float* __restrict__ x, const int* __restrict__ caption,
    const float* __restrict__ emb, unsigned short* __restrict__ X) {
  int i = blockIdx.x * 256 + threadIdx.x;  // over TB_*512
  if (i >= TB_ * 512) return;
  int r = i >> 9, e = i & 511;
  int t = r >> 6, b = r & 63;
  float v = (t == 0) ? x[b * 512 + e]
                     : emb[(size_t)caption[b * T_ + t] * 512 + e];
  X[i] = f2bf(v);
}

// Zero Hs block 0 (the h_{-1} = 0 state) and the grid-barrier counter.
// Runs every graph replay, so the monotonic counter restarts at 0 each run.
__global__ __launch_bounds__(256) void zero_state_kernel(
    unsigned short* __restrict__ hs0, int* __restrict__ cnt) {
  int i = blockIdx.x * 256 + threadIdx.x;
  if (i < B_ * H_) hs0[i] = 0;
  if (i == 0) *cnt = 0;
}

// ------------------- GEMM: G0 = X @ W_ih^T + b_ih + b_hh -------------------
// m97 structure: 128x128 tile, BK=32, 4 waves (2x2 of 64x64), 16x16x32 MFMA.

__global__ __launch_bounds__(256) void gemm_g0_kernel(
    const unsigned short* __restrict__ A,    // X_bf [3200][512]
    const unsigned short* __restrict__ Bm,   // Wih_bf [2048][512] (n-major)
    const float* __restrict__ b_ih, const float* __restrict__ b_hh,
    float* __restrict__ G0) {                // [3200][2048]
  __shared__ __align__(16) unsigned short As[128 * 32];
  __shared__ __align__(16) unsigned short Bs[128 * 32];
  const int tid = threadIdx.x;
  const int lane = tid & 63;
  const int w = tid >> 6;
  const int wm = (w >> 1) * 64;
  const int wn = (w & 1) * 64;
  const int m0 = blockIdx.y * 128;
  const int n0 = blockIdx.x * 128;
  const int srow = w * 16 + (lane >> 2);     // staging: lds off = w*1024 + lane*16
  const int skoff = (lane & 3) * 8;

  const f32x4 fzero = {0.f, 0.f, 0.f, 0.f};
  f32x4 acc[4][4];
#pragma unroll
  for (int i = 0; i < 4; i++)
#pragma unroll
    for (int j = 0; j < 4; j++) acc[i][j] = fzero;

  for (int k0 = 0; k0 < 512; k0 += 32) {
    async_copy16(A + (size_t)(m0 + srow) * 512 + k0 + skoff, &As[srow * 32 + skoff]);
    async_copy16(A + (size_t)(m0 + srow + 64) * 512 + k0 + skoff, &As[(srow + 64) * 32 + skoff]);
    async_copy16(Bm + (size_t)(n0 + srow) * 512 + k0 + skoff, &Bs[srow * 32 + skoff]);
    async_copy16(Bm + (size_t)(n0 + srow + 64) * 512 + k0 + skoff, &Bs[(srow + 64) * 32 + skoff]);
    __syncthreads();
    const int fr = lane & 15;
    const int fk = (lane >> 4) * 8;
    bf16x8 af[4], bfv[4];
#pragma unroll
    for (int i = 0; i < 4; i++) {
      af[i] = *(const bf16x8*)&As[(wm + i * 16 + fr) * 32 + fk];
      bfv[i] = *(const bf16x8*)&Bs[(wn + i * 16 + fr) * 32 + fk];
    }
#pragma unroll
    for (int i = 0; i < 4; i++)
#pragma unroll
      for (int j = 0; j < 4; j++)
        acc[i][j] = __builtin_amdgcn_mfma_f32_16x16x32_bf16(af[i], bfv[j], acc[i][j], 0, 0, 0);
    __syncthreads();
  }
  const int quad = lane >> 4;
  const int colj = lane & 15;
#pragma unroll
  for (int j = 0; j < 4; j++) {
    const int n = n0 + wn + j * 16 + colj;
    const float bv = b_ih[n] + b_hh[n];
#pragma unroll
    for (int i = 0; i < 4; i++) {
      const int rb = m0 + wm + i * 16 + quad * 4;
#pragma unroll
      for (int p = 0; p < 4; p++)
        G0[(size_t)(rb + p) * 2048 + n] = acc[i][j][p] + bv;
    }
  }
}

// --------------------- persistent LSTM kernel ------------------------------
// ONE kernel for all 50 steps. grid = 32 WGs x 256 (4 waves), one WG per CU,
// guaranteed co-resident (32 <= 256 CUs, 1 wave/SIMD, no LDS) -> the spin
// barrier cannot deadlock.
//   WG j0=bid*16 owns h-columns [j0,j0+16) across all 4 gates.
//   Wave w owns batch rows [w*16, w*16+16).
//   W_hh B-fragments are step-invariant: hoisted into 256 VGPRs ONCE.
//   c lives in 4 VGPRs per lane (lane exclusively owns its (b,j) cells).
//   h exchange: step t reads HsX block t, writes block t+1 (disjoint).
// Coherence strategy (round-2 change): h loads/stores are AGENT-scope
// relaxed atomics (sc0 sc1 -> bypass the non-coherent per-XCD L1/L2 and
// hit the device coherent point directly). Therefore the barrier needs NO
// __threadfence(): release = s_waitcnt vmcnt(0) (stores are already
// device-visible once complete) + relaxed atomicAdd; acquire = nothing
// (reads can't see stale cache). This removes the per-step buffer_wbl2 +
// whole-L2 buffer_inv that made round 1 cost 8.1 us/step.

__global__ __launch_bounds__(256, 1) void lstm_persistent_kernel(
    const unsigned short* __restrict__ Whh,    // [2048][512] bf16
    const float* __restrict__ G0,              // [3200][2048]
    unsigned short* __restrict__ HsX,          // [(T_+1)*64][512] bf16
    int* __restrict__ cnt) {                   // grid barrier counter (zeroed)
  const int tid = threadIdx.x;
  const int lane = tid & 63;
  const int w = tid >> 6;
  const int j0 = blockIdx.x * 16;
  const int fr = lane & 15;
  const int quad = lane >> 4;
  const int fk = quad * 8;
  const int j = j0 + fr;                       // h column this lane owns

  // Hoist step-invariant W_hh fragments: 4 gates x 16 k-slices x 4 VGPRs.
  bf16x8 bfrag[4][16];
#pragma unroll
  for (int g = 0; g < 4; g++)
#pragma unroll
    for (int ks = 0; ks < 16; ks++)
      bfrag[g][ks] = *(const bf16x8*)&Whh[(size_t)(g * 512 + j0 + fr) * 512 + ks * 32 + fk];

  float creg[4] = {0.f, 0.f, 0.f, 0.f};       // c for (b = w*16+quad*4+p, j)
  const f32x4 fzero = {0.f, 0.f, 0.f, 0.f};

  // G0 double-buffer: gate pre-activations for the CURRENT step live in g0v;
  // the NEXT step's are prefetched early each iteration (normal cacheable
  // loads — G0 was produced in stream order, no coherence hazard).
  float g0v[4][4], g0n[4][4];                  // [gate][p]
#pragma unroll
  for (int p = 0; p < 4; p++) {
    const float* g0r = G0 + (size_t)(w * 16 + quad * 4 + p) * 2048 + j;
#pragma unroll
    for (int g = 0; g < 4; g++) g0v[g][p] = g0r[g * 512];
  }

  for (int t = 0; t < T_; t++) {
    // A fragments: h_{t-1} = HsX block t, via agent-coherent 8B loads.
    const unsigned short* arow = HsX + (size_t)(t * 64 + w * 16 + fr) * 512 + fk;
    bf16x8 af[16];
#pragma unroll
    for (int ks = 0; ks < 16; ks++) {
      union { unsigned long long u[2]; bf16x8 v; } tmp;
      tmp.u[0] = __hip_atomic_load((const unsigned long long*)(arow + (size_t)ks * 32),
                                   __ATOMIC_RELAXED, __HIP_MEMORY_SCOPE_AGENT);
      tmp.u[1] = __hip_atomic_load((const unsigned long long*)(arow + (size_t)ks * 32 + 4),
                                   __ATOMIC_RELAXED, __HIP_MEMORY_SCOPE_AGENT);
      af[ks] = tmp.v;
    }

    // Prefetch NEXT step's G0 while this step's MFMAs run.
    if (t + 1 < T_) {
#pragma unroll
      for (int p = 0; p < 4; p++) {
        const float* g0r = G0 + (size_t)((t + 1) * 64 + w * 16 + quad * 4 + p) * 2048 + j;
#pragma unroll
        for (int g = 0; g < 4; g++) g0n[g][p] = g0r[g * 512];
      }
    }

    f32x4 acc[4] = {fzero, fzero, fzero, fzero};
#pragma unroll
    for (int ks = 0; ks < 16; ks++)
#pragma unroll
      for (int g = 0; g < 4; g++)
        acc[g] = __builtin_amdgcn_mfma_f32_16x16x32_bf16(af[ks], bfrag[g][ks], acc[g], 0, 0, 0);

#pragma unroll
    for (int p = 0; p < 4; p++) {
      float iv = acc[0][p] + g0v[0][p];
      float fv = acc[1][p] + g0v[1][p];
      float gv = acc[2][p] + g0v[2][p];
      float ov = acc[3][p] + g0v[3][p];
      iv = 1.f / (1.f + __expf(-iv));
      fv = 1.f / (1.f + __expf(-fv));
      gv = tanhf(gv);
      ov = 1.f / (1.f + __expf(-ov));
      float cn = fv * creg[p] + iv * gv;
      creg[p] = cn;
      float hn = ov * tanhf(cn);
      const int b = w * 16 + quad * 4 + p;
      // Agent-coherent store: device-visible on completion, no fence needed.
      __hip_atomic_store(&HsX[(size_t)((t + 1) * 64 + b) * 512 + j], f2bf(hn),
                         __ATOMIC_RELAXED, __HIP_MEMORY_SCOPE_AGENT);
    }

    // Rotate the G0 double-buffer (register moves).
#pragma unroll
    for (int g = 0; g < 4; g++)
#pragma unroll
      for (int p = 0; p < 4; p++) g0v[g][p] = g0n[g][p];

    // Grid barrier (skip after the last step; kernel end + stream order
    // cover gemm_out). Monotonic target avoids counter-reset races.
    if (t != T_ - 1) {
      __syncthreads();                         // implicit vmcnt(0): all waves'
                                               // coherent h-stores complete
      if (tid == 0) {
        asm volatile("s_waitcnt vmcnt(0)" ::: "memory");
        __hip_atomic_fetch_add(cnt, 1, __ATOMIC_RELAXED, __HIP_MEMORY_SCOPE_AGENT);
        const int target = 32 * (t + 1);
        while (__hip_atomic_load(cnt, __ATOMIC_RELAXED, __HIP_MEMORY_SCOPE_AGENT) < target)
          __builtin_amdgcn_s_sleep(1);
      }
      __builtin_amdgcn_sched_barrier(0);       // pin post-barrier loads after spin
      __syncthreads();
    }
  }
}

// ----------------- GEMM: out[b,t,v] = Hs @ W_fc^T + b_fc -------------------

__global__ __launch_bounds__(256) void gemm_out_kernel(
    const unsigned short* __restrict__ A,    // Hs [3200][512]
    const unsigned short* __restrict__ Bm,   // Wfc_bf [30080][512] (padded)
    const float* __restrict__ bias,          // b_fc [30000]
    float* __restrict__ out) {               // [64][50][30000]
  __shared__ __align__(16) unsigned short As[128 * 32];
  __shared__ __align__(16) unsigned short Bs[128 * 32];
  const int tid = threadIdx.x;
  const int lane = tid & 63;
  const int w = tid >> 6;
  const int wm = (w >> 1) * 64;
  const int wn = (w & 1) * 64;
  const int m0 = blockIdx.y * 128;
  const int n0 = blockIdx.x * 128;
  const int srow = w * 16 + (lane >> 2);
  const int skoff = (lane & 3) * 8;

  const f32x4 fzero = {0.f, 0.f, 0.f, 0.f};
  f32x4 acc[4][4];
#pragma unroll
  for (int i = 0; i < 4; i++)
#pragma unroll
    for (int j = 0; j < 4; j++) acc[i][j] = fzero;

  for (int k0 = 0; k0 < 512; k0 += 32) {
    async_copy16(A + (size_t)(m0 + srow) * 512 + k0 + skoff, &As[srow * 32 + skoff]);
    async_copy16(A + (size_t)(m0 + srow + 64) * 512 + k0 + skoff, &As[(srow + 64) * 32 + skoff]);
    async_copy16(Bm + (size_t)(n0 + srow) * 512 + k0 + skoff, &Bs[srow * 32 + skoff]);
    async_copy16(Bm + (size_t)(n0 + srow + 64) * 512 + k0 + skoff, &Bs[(srow + 64) * 32 + skoff]);
    __syncthreads();
    const int fr = lane & 15;
    const int fk = (lane >> 4) * 8;
    bf16x8 af[4], bfv[4];
#pragma unroll
    for (int i = 0; i < 4; i++) {
      af[i] = *(const bf16x8*)&As[(wm + i * 16 + fr) * 32 + fk];
      bfv[i] = *(const bf16x8*)&Bs[(wn + i * 16 + fr) * 32 + fk];
    }
#pragma unroll
    for (int i = 0; i < 4; i++)
#pragma unroll
      for (int j = 0; j < 4; j++)
        acc[i][j] = __builtin_amdgcn_mfma_f32_16x16x32_bf16(af[i], bfv[j], acc[i][j], 0, 0, 0);
    __syncthreads();
  }
  const int quad = lane >> 4;
  const int colj = lane & 15;
#pragma unroll
  for (int j = 0; j < 4; j++) {
    const int v = n0 + wn + j * 16 + colj;
    if (v >= V_) continue;                 // only last col-tile partially valid
    const float bv = bias[v];
#pragma unroll
    for (int i = 0; i < 4; i++) {
      const int rb = m0 + wm + i * 16 + quad * 4;
#pragma unroll
      for (int p = 0; p < 4; p++) {
        const int r = rb + p;              // r = t*64 + b
        const int tt = r >> 6, bb = r & 63;
        out[(size_t)(bb * T_ + tt) * V_ + v] = acc[i][j][p] + bv;
      }
    }
  }
}

// ------------------------------- launch ------------------------------------

extern "C" void kernel_launch(void* const* d_in, const int* in_sizes, int n_in,
                              void* d_out, int out_size, void* d_ws, size_t ws_size,
                              hipStream_t stream) {
  const float* x       = (const float*)d_in[0];
  const int*   caption = (const int*)d_in[1];
  const float* emb     = (const float*)d_in[2];
  const float* W_ih    = (const float*)d_in[3];
  const float* W_hh    = (const float*)d_in[4];
  const float* b_ih    = (const float*)d_in[5];
  const float* b_hh    = (const float*)d_in[6];
  const float* W_fc    = (const float*)d_in[7];
  const float* b_fc    = (const float*)d_in[8];
  float* out = (float*)d_out;

  char* p = (char*)d_ws;
  auto alloc = [&](size_t bytes) {
    char* r = p;
    p += (bytes + 255) & ~(size_t)255;
    return r;
  };
  unsigned short* Wih_bf = (unsigned short*)alloc((size_t)2048 * 512 * 2);
  unsigned short* Whh_bf = (unsigned short*)alloc((size_t)2048 * 512 * 2);
  unsigned short* Wfc_bf = (unsigned short*)alloc((size_t)VPAD * 512 * 2);
  unsigned short* X_bf   = (unsigned short*)alloc((size_t)TB_ * 512 * 2);
  unsigned short* HsX    = (unsigned short*)alloc((size_t)(TB_ + 64) * 512 * 2);
  int*            cnt    = (int*)alloc(256);
  float* G0              = (float*)alloc((size_t)TB_ * 2048 * 4);
  // total ws use: ~68 MB

  unsigned short* Hs = HsX + (size_t)64 * 512;   // blocks 1..T_ = h_0..h_{T-1}

  convert_bf16_kernel<<<(2048 * 512 + 255) / 256, 256, 0, stream>>>(W_ih, Wih_bf, 2048 * 512);
  convert_bf16_kernel<<<(2048 * 512 + 255) / 256, 256, 0, stream>>>(W_hh, Whh_bf, 2048 * 512);
  convert_pad_wfc_kernel<<<(VPAD * 512 + 255) / 256, 256, 0, stream>>>(W_fc, Wfc_bf);
  build_x_kernel<<<(TB_ * 512 + 255) / 256, 256, 0, stream>>>(x, caption, emb, X_bf);
  zero_state_kernel<<<(B_ * H_ + 255) / 256, 256, 0, stream>>>(HsX, cnt);

  gemm_g0_kernel<<<dim3(16, 25), 256, 0, stream>>>(X_bf, Wih_bf, b_ih, b_hh, G0);

  lstm_persistent_kernel<<<32, 256, 0, stream>>>(Whh_bf, G0, HsX, cnt);

  gemm_out_kernel<<<dim3(235, 25), 256, 0, stream>>>(Hs, Wfc_bf, b_fc, out);
}